// Round 9
// baseline (162.910 us; speedup 1.0000x reference)
//
#include <hip/hip_runtime.h>
#include <cstddef>

#define EPSF 1e-12f
#define NCB 90
#define NT 30
#define ODIM 256
#define DDIM 8192

typedef unsigned short u16;
typedef __attribute__((ext_vector_type(8))) short short8;
typedef __attribute__((ext_vector_type(4))) float float4v;

__device__ inline u16 f2bf(float f) {
  union { float f; unsigned u; } v; v.f = f;
  unsigned r = v.u + 0x7FFFu + ((v.u >> 16) & 1u);
  return (u16)(r >> 16);
}
__device__ inline float bf2f(u16 h) {
  union { unsigned u; float f; } v; v.u = ((unsigned)h) << 16;
  return v.f;
}

// ---------------------------------------------------------------------------
// K1 (MFMA): R7's 8-wave single-buffer schedule (46us) with LDS compacted
// 33.3KB -> 26.5KB via time-aliasing:
//   afr   (4KB, live in phase3, read under barrier)  overlays xtf (live phase1)
//   pasum (2KB, live post-loop)                      overlays As  (dead then)
// Every alias pair is separated by a __syncthreads. Purpose: fit 2 blocks/CU
// even under a 64KB-effective LDS budget (residency was measured ~1 block:
// occupancy 15% = ~5 waves/CU despite 22 theoretical). Math & output order
// bit-identical to R7/R8.
// ---------------------------------------------------------------------------
__global__ __launch_bounds__(512, 2) void k1_assign(
    const float* __restrict__ x,       // [8][128][16][900]
    const float* __restrict__ conv_w,  // [64][128]
    const float* __restrict__ conv_b,  // [64]
    float* __restrict__ P,             // [8][90][64][128]
    float* __restrict__ PA)            // [8][90][64]
{
  __shared__ __align__(16) char smem[27136];
  u16*   xtf   = (u16*)smem;              // [4160] logits A-frags, live phase1
  u16*   afr   = (u16*)smem;              // [2048] a-frags, ALIAS of xtf (phase3)
  u16*   xf    = (u16*)(smem + 8320);     // [5120] P B-frags
  float* As    = (float*)(smem + 18560);  // [64*33] logits -> exp
  float* pasum = (float*)(smem + 18560);  // [512] ALIAS of As (post-loop)
  float* invs  = (float*)(smem + 27008);  // [32] 1/sum per column

  const int bx0 = blockIdx.x;      // [0,720)
  const int n = bx0 & 7;           // XCD pin
  const int cb = bx0 >> 3;
  const int t = threadIdx.x;
  const int lane = t & 63;
  const int w8 = t >> 6;           // wave 0..7

  const float* xn = x + (size_t)n * 1843200 + cb * 10;

  const int colt = w8 & 1;         // logits column tile
  const int kt = w8 >> 1;          // k-tile 0..3
  const int kr = kt * 16 + (lane & 15);
  const float bk = conv_b[kr];

  short8 wh[4], wl[4];
  {
    const int cbase = (lane >> 4) << 3;
#pragma unroll
    for (int cb32 = 0; cb32 < 4; ++cb32) {
      const float* wp = conv_w + (size_t)kr * 128 + cb32 * 32 + cbase;
      float4 u0 = *(const float4*)wp;
      float4 u1 = *(const float4*)(wp + 4);
      float fv[8] = {u0.x, u0.y, u0.z, u0.w, u1.x, u1.y, u1.z, u1.w};
      union { u16 u[8]; short8 v; } hh, ll;
#pragma unroll
      for (int j = 0; j < 8; ++j) {
        u16 h = f2bf(fv[j]);
        hh.u[j] = h;
        ll.u[j] = f2bf(fv[j] - bf2f(h));
      }
      wh[cb32] = hh.v; wl[cb32] = ll.v;
    }
  }

  float4v pacc[4];
#pragma unroll
  for (int i = 0; i < 4; ++i) pacc[i] = (float4v){0.f, 0.f, 0.f, 0.f};
  float pak = 0.f;

  // ---- prologue: load cc=0 x into registers ----
  float2 xr[4];
#pragma unroll
  for (int s = 0; s < 4; ++s) {
    int e2 = t + 512 * s;
    int c = e2 >> 4, p = e2 & 15;
    int cl = 2 * p;
    int h = cl / 10, wi = cl - 10 * h;
    xr[s] = *(const float2*)(xn + (size_t)c * 14400 + h * 900 + wi);
  }

  for (int cc = 0; cc < 5; ++cc) {
    __syncthreads();                     // prev P-mfma (afr reads) done before restage
    // ---- write prefetched regs to both LDS layouts ----
#pragma unroll
    for (int s = 0; s < 4; ++s) {
      int e2 = t + 512 * s;
      int c = e2 >> 4, p = e2 & 15;
      int cl = 2 * p;
      u16 h0 = f2bf(xr[s].x), h1 = f2bf(xr[s].y);
      int ip = (c >> 4) * 640 + (p >> 2) * 160 + (c & 15) * 8 + (cl & 7);
      ushort2 pr; pr.x = h0; pr.y = h1;
      *(ushort2*)&xf[ip] = pr;
      int F = (p >> 3) * 4 + (c >> 5);
      int L = (((c >> 3) & 3) << 4) + (cl & 15);
      int i0 = F * 520 + L * 8 + (c & 7);
      xtf[i0] = h0;
      xtf[i0 + 8] = h1;
    }
    // ---- issue next cc's loads; they retire behind this cc's compute ----
    if (cc < 4) {
#pragma unroll
      for (int s = 0; s < 4; ++s) {
        int e2 = t + 512 * s;
        int c = e2 >> 4, p = e2 & 15;
        int g = (cc + 1) * 32 + 2 * p;
        int h = g / 10, wi = g - 10 * h;
        xr[s] = *(const float2*)(xn + (size_t)c * 14400 + h * 900 + wi);
      }
    }
    __syncthreads();

    // ---- logits MFMA: wave (colt, kt) computes 16 k-rows x 16 cols ----
    {
      float4v d0 = (float4v){0.f, 0.f, 0.f, 0.f};
#pragma unroll
      for (int cb32 = 0; cb32 < 4; ++cb32) {
        short8 xa = *(short8*)&xtf[(colt * 4 + cb32) * 520 + lane * 8];
        d0 = __builtin_amdgcn_mfma_f32_16x16x32_bf16(xa, wh[cb32], d0, 0, 0, 0);
        d0 = __builtin_amdgcn_mfma_f32_16x16x32_bf16(xa, wl[cb32], d0, 0, 0, 0);
      }
      int colb = colt * 16 + ((lane >> 4) << 2);
#pragma unroll
      for (int r = 0; r < 4; ++r)
        As[kr * 33 + colb + r] = d0[r] + bk;
    }
    __syncthreads();

    // ---- wave-local softmax over k for cols [4*w8, 4*w8+4) ----
    {
      const int col4 = lane & 3;
      const int kq = lane >> 2;          // 16 groups of 4 k
      const int colg = w8 * 4 + col4;
      float m = -3.4e38f;
#pragma unroll
      for (int i = 0; i < 4; ++i) m = fmaxf(m, As[(kq * 4 + i) * 33 + colg]);
      m = fmaxf(m, __shfl_xor(m, 4));
      m = fmaxf(m, __shfl_xor(m, 8));
      m = fmaxf(m, __shfl_xor(m, 16));
      m = fmaxf(m, __shfl_xor(m, 32));
      float s = 0.f;
#pragma unroll
      for (int i = 0; i < 4; ++i) {
        int a = (kq * 4 + i) * 33 + colg;
        float e = __expf(As[a] - m);
        As[a] = e;
        s += e;
      }
      s += __shfl_xor(s, 4);
      s += __shfl_xor(s, 8);
      s += __shfl_xor(s, 16);
      s += __shfl_xor(s, 32);
      if (kq == 0) invs[colg] = 1.f / s;
    }
    __syncthreads();                 // As reads done before afr (aliases xtf... no:
                                     // afr write below aliases xtf, whose reads ended
                                     // at the logits barrier; this barrier orders the
                                     // As reads in a-frag build vs nothing new, but
                                     // keeps the R7 3-barrier structure intact)
    // ---- a-frag build (reads As, writes afr = alias of dead xtf) ----
    {
      union { u16 u[4]; ushort4 v; } cvt;
      float paks = 0.f;
#pragma unroll
      for (int j = 0; j < 4; ++j) {
        float a = As[lane * 33 + w8 * 4 + j] * invs[w8 * 4 + j];
        paks += a;
        cvt.u[j] = f2bf(a);
      }
      pak += paks;
      int dst = ((lane >> 4) * 64 + ((w8 >> 1) << 4) + (lane & 15)) * 8 + (w8 & 1) * 4;
      *(ushort4*)&afr[dst] = cvt.v;
    }
    __syncthreads();

    // ---- P MFMA: wave (kt, w8&1) owns k-tile kt, 4 of 8 c-tiles ----
    {
      short8 aa = *(short8*)&afr[((w8 >> 1) * 64 + lane) * 8];
#pragma unroll
      for (int c4 = 0; c4 < 4; ++c4) {
        int ct = (w8 & 1) * 4 + c4;
        short8 xb = *(short8*)&xf[ct * 640 + (lane >> 4) * 160 + (lane & 15) * 8];
        pacc[c4] = __builtin_amdgcn_mfma_f32_16x16x32_bf16(aa, xb, pacc[c4], 0, 0, 0);
      }
    }
  }

  float* Pp = P + (size_t)(n * NCB + cb) * DDIM;
  {
    int krow = (w8 >> 1) * 16 + ((lane >> 4) << 2);
    int c0 = (w8 & 1) * 64 + (lane & 15);
#pragma unroll
    for (int c4 = 0; c4 < 4; ++c4)
#pragma unroll
      for (int r = 0; r < 4; ++r)
        Pp[(krow + r) * 128 + c0 + c4 * 16] = pacc[c4][r];
  }
  __syncthreads();                 // last As reads (cc=4 softmax) long done; ensure
                                   // all waves past P-mfma before pasum overlays As
  pasum[t] = pak;
  __syncthreads();
  if (t < 64) {
    float s = 0.f;
#pragma unroll
    for (int i = 0; i < 8; ++i) s += pasum[t + 64 * i];
    PA[(size_t)(n * NCB + cb) * 64 + t] = s;
  }
}

// ---------------------------------------------------------------------------
// K2: R5/R6/R7/R8 form. Traffic- and TLP-insensitive; at its floor. Unchanged.
// ---------------------------------------------------------------------------
__global__ __launch_bounds__(256) void k2_vlad(
    const float* __restrict__ P, const float* __restrict__ PA,
    const float* __restrict__ centers, u16* __restrict__ vlad16,
    float* __restrict__ gss)            // [240][8]
{
  __shared__ float Ak[8];
  __shared__ float red[4];
  const int bx0 = blockIdx.x;                    // [0,1920)
  const int id = (bx0 & 7) * 240 + (bx0 >> 3);   // XCD pin: n = bx0&7
  const int n = id / 240;
  const int rem = id - n * 240;
  const int wt = rem >> 3, eb = rem & 7;
  const int win = n * NT + wt;
  const int t = threadIdx.x;

  if (t < 32) {
    int kk = t >> 2, ii = t & 3;
    float s = 0.f;
#pragma unroll
    for (int ss = 0; ss < 5; ++ss) {
      int i = ii + 4 * ss;
      int cb = (3 * wt + 80 + i) % 90;
      s += PA[((size_t)n * NCB + cb) * 64 + eb * 8 + kk];
    }
    s += __shfl_xor(s, 1);
    s += __shfl_xor(s, 2);
    if (ii == 0) Ak[kk] = s;
  }
  __syncthreads();

  const int e0 = eb * 1024 + t * 4;     // global (k,c) offset in [0,8192)
  const float* base = P + (size_t)n * NCB * DDIM + e0;
  float v[4];
#pragma unroll
  for (int j = 0; j < 4; ++j) v[j] = 0.f;
#pragma unroll 5
  for (int i = 0; i < 20; ++i) {
    int cb = (3 * wt + 80 + i) % 90;
    float4 u0 = *(const float4*)(base + (size_t)cb * DDIM);
    v[0] += u0.x; v[1] += u0.y; v[2] += u0.z; v[3] += u0.w;
  }

  const float A = Ak[t >> 5];           // k_local = t/32
  const float* ce = centers + e0;
  float ss8 = 0.f;
#pragma unroll
  for (int j = 0; j < 4; ++j) {
    float val = v[j] - ce[j] * A;
    v[j] = val;
    ss8 += val * val;
  }
  // per-k (32-thread group) reduction for intra-norm
  float ssg = ss8;
  ssg += __shfl_xor(ssg, 1);
  ssg += __shfl_xor(ssg, 2);
  ssg += __shfl_xor(ssg, 4);
  ssg += __shfl_xor(ssg, 8);
  ssg += __shfl_xor(ssg, 16);
  float rn = 1.f / fmaxf(sqrtf(ssg), EPSF);
  // block-wide sum of normalized squares (for global norm)
  float ts = ss8 * rn * rn;
  ts += __shfl_xor(ts, 1);
  ts += __shfl_xor(ts, 2);
  ts += __shfl_xor(ts, 4);
  ts += __shfl_xor(ts, 8);
  ts += __shfl_xor(ts, 16);
  ts += __shfl_xor(ts, 32);
  if ((t & 63) == 0) red[t >> 6] = ts;
  __syncthreads();
  if (t == 0) gss[(size_t)win * 8 + eb] = red[0] + red[1] + red[2] + red[3];

  union { u16 u[4]; ushort4 v4; } o;
#pragma unroll
  for (int j = 0; j < 4; ++j) o.u[j] = f2bf(v[j] * rn);
  *(ushort4*)(vlad16 + (size_t)win * DDIM + e0) = o.v4;
}

// ---------------------------------------------------------------------------
// K3 (MFMA): R6/R7/R8 form (3 rt-tiles per block, XCD-pinned weight slices).
// Unchanged.
// ---------------------------------------------------------------------------
__global__ __launch_bounds__(256) void k3_gemm(
    const u16* __restrict__ vlad16, const float* __restrict__ gss,
    const float* __restrict__ mlp_w, float* __restrict__ part)
{
  __shared__ float ga[48];
  const int bx = blockIdx.x;         // [0,320)
  const int xcd = bx & 7;
  const int q = bx >> 3;             // [0,40)
  const int rtg = q % 5;             // rt-group: rows [rtg*48, rtg*48+48)
  const int h = (q / 5) * 8 + xcd;   // [0,64): same h -> same XCD, adjacent
  const int ot = h & 1;              // o half
  const int ks = h >> 1;             // K-slice of 256
  const int t = threadIdx.x;
  const int lane = t & 63;
  const int w = t >> 6;

  if (t < 48) {
    int r = rtg * 48 + t;
    float s = 0.f;
#pragma unroll
    for (int j = 0; j < 8; ++j) s += gss[(size_t)r * 8 + j];
    ga[t] = 1.f / fmaxf(sqrtf(s), EPSF);
  }
  __syncthreads();

  const int m = lane & 15;
  const int kg = lane >> 4;
  const int d0 = ks * 256 + kg * 8;
  const u16* a0 = vlad16 + (size_t)(rtg * 48 + m) * DDIM + d0;

  float4v acc[3][2];
#pragma unroll
  for (int mi = 0; mi < 3; ++mi)
#pragma unroll
    for (int i = 0; i < 2; ++i) acc[mi][i] = (float4v){0.f, 0.f, 0.f, 0.f};

#pragma unroll
  for (int ko = 0; ko < 8; ++ko) {
    short8 a[3];
#pragma unroll
    for (int mi = 0; mi < 3; ++mi)
      a[mi] = *(const short8*)(a0 + (size_t)(mi * 16) * DDIM + ko * 32);
#pragma unroll
    for (int nt = 0; nt < 2; ++nt) {
      int o = ot * 128 + w * 32 + nt * 16 + m;
      const float* wrow = mlp_w + (size_t)o * DDIM + d0 + ko * 32;
      float4 u0 = *(const float4*)wrow;
      float4 u1 = *(const float4*)(wrow + 4);
      union { u16 u[8]; short8 v; } bb;
      bb.u[0] = f2bf(u0.x); bb.u[1] = f2bf(u0.y); bb.u[2] = f2bf(u0.z); bb.u[3] = f2bf(u0.w);
      bb.u[4] = f2bf(u1.x); bb.u[5] = f2bf(u1.y); bb.u[6] = f2bf(u1.z); bb.u[7] = f2bf(u1.w);
#pragma unroll
      for (int mi = 0; mi < 3; ++mi)
        acc[mi][nt] = __builtin_amdgcn_mfma_f32_16x16x32_bf16(a[mi], bb.v, acc[mi][nt], 0, 0, 0);
    }
  }

  float* pp = part + ((size_t)ks * 240 + rtg * 48) * ODIM;
#pragma unroll
  for (int mi = 0; mi < 3; ++mi)
#pragma unroll
    for (int nt = 0; nt < 2; ++nt) {
      int o = ot * 128 + w * 32 + nt * 16 + m;
#pragma unroll
      for (int r = 0; r < 4; ++r) {
        int rl = mi * 16 + kg * 4 + r;
        pp[rl * ODIM + o] = acc[mi][nt][r] * ga[rl];
      }
    }
}

// ---------------------------------------------------------------------------
// K4: R5-R8 form (1024 threads, 4-way split sum). At its floor. Unchanged.
// ---------------------------------------------------------------------------
__global__ __launch_bounds__(1024) void k4_out(
    const float* __restrict__ part, const float* __restrict__ bias,
    float* __restrict__ out)
{
  __shared__ float acc[4][256];
  __shared__ float red[4];
  const int r = blockIdx.x;
  const int t = threadIdx.x;
  const int o = t & 255, sq = t >> 8;

  float v = 0.f;
#pragma unroll
  for (int s = 0; s < 8; ++s)
    v += part[((size_t)(sq * 8 + s) * 240 + r) * ODIM + o];
  acc[sq][o] = v;
  __syncthreads();

  float ss = 0.f;
  if (t < 256) {
    v = acc[0][o] + acc[1][o] + acc[2][o] + acc[3][o] + bias[o];
    ss = v * v;
    ss += __shfl_xor(ss, 32);
    ss += __shfl_xor(ss, 16);
    ss += __shfl_xor(ss, 8);
    ss += __shfl_xor(ss, 4);
    ss += __shfl_xor(ss, 2);
    ss += __shfl_xor(ss, 1);
    if ((t & 63) == 0) red[t >> 6] = ss;
  }
  __syncthreads();
  if (t < 256) {
    float total = red[0] + red[1] + red[2] + red[3];
    out[(size_t)r * ODIM + o] = v / fmaxf(sqrtf(total), EPSF);
  }
}

// ---------------------------------------------------------------------------
extern "C" void kernel_launch(void* const* d_in, const int* in_sizes, int n_in,
                              void* d_out, int out_size, void* d_ws, size_t ws_size,
                              hipStream_t stream) {
  const float* x       = (const float*)d_in[0];
  const float* centers = (const float*)d_in[1];
  const float* conv_w  = (const float*)d_in[2];
  const float* conv_b  = (const float*)d_in[3];
  const float* mlp_w   = (const float*)d_in[4];
  const float* mlp_b   = (const float*)d_in[5];
  float* out = (float*)d_out;

  float* ws     = (float*)d_ws;
  float* P      = ws;                       // 5,898,240 floats (23.6 MB)
  float* PA     = ws + 5898240;             // 46,080 floats
  u16*   vlad16 = (u16*)(ws + 5944320);     // 240*8192 u16 (3.9 MB)
  float* gss    = (float*)(ws + 6927360);   // 240*8 floats
  float* part   = ws;                       // [32][240][256] overlays dead P

  k1_assign<<<dim3(8 * NCB),    dim3(512),  0, stream>>>(x, conv_w, conv_b, P, PA);
  k2_vlad  <<<dim3(8 * NT * 8), dim3(256),  0, stream>>>(P, PA, centers, vlad16, gss);
  k3_gemm  <<<dim3(320),        dim3(256),  0, stream>>>(vlad16, gss, mlp_w, part);
  k4_out   <<<dim3(240),        dim3(1024), 0, stream>>>(part, mlp_b, out);
}

// Round 10
// 154.728 us; speedup vs baseline: 1.0529x; 1.0529x over previous
//
#include <hip/hip_runtime.h>
#include <cstddef>

#define EPSF 1e-12f
#define NCB 90
#define NT 30
#define ODIM 256
#define DDIM 8192

typedef unsigned short u16;
typedef __attribute__((ext_vector_type(8))) short short8;
typedef __attribute__((ext_vector_type(4))) float float4v;

__device__ inline u16 f2bf(float f) {
  union { float f; unsigned u; } v; v.f = f;
  unsigned r = v.u + 0x7FFFu + ((v.u >> 16) & 1u);
  return (u16)(r >> 16);
}
__device__ inline float bf2f(u16 h) {
  union { unsigned u; float f; } v; v.u = ((unsigned)h) << 16;
  return v.f;
}

// ---------------------------------------------------------------------------
// K1 (MFMA): 3 adjacent cb slabs per block -> grid 240 <= 256 CUs: ONE block
// round (R9 ran 2.8 rounds at ~1 resident block/CU), and 3 independent
// instruction chains per phase convert the lost TLP into ILP. Barriers per
// unit work /3. LDS 3x27136=81.4KB (64KB-budget theory falsified in R9).
// Per-slab math and P/PA outputs bit-identical to R9.
// ---------------------------------------------------------------------------
__global__ __launch_bounds__(512, 2) void k1_assign(
    const float* __restrict__ x,       // [8][128][16][900]
    const float* __restrict__ conv_w,  // [64][128]
    const float* __restrict__ conv_b,  // [64]
    float* __restrict__ P,             // [8][90][64][128]
    float* __restrict__ PA)            // [8][90][64]
{
  __shared__ __align__(16) char smem[81408];   // 3 x 27136, per-slab layout:
  // +0     xtf[4160] u16 (logits A-frags; afr[2048] aliases it in phase 3)
  // +8320  xf[5120]  u16 (P B-frags)
  // +18560 As[64*33] f32 (logits->exp; pasum[512] aliases it post-loop)
  // +27008 invs[32]  f32

  const int bx0 = blockIdx.x;      // [0,240)
  const int n = bx0 & 7;           // XCD pin
  const int q = bx0 >> 3;          // [0,30): slabs 3q, 3q+1, 3q+2
  const int t = threadIdx.x;
  const int lane = t & 63;
  const int w8 = t >> 6;           // wave 0..7

  const float* xn0 = x + (size_t)n * 1843200 + (size_t)(3 * q) * 10;

  const int colt = w8 & 1;         // logits column tile
  const int kt = w8 >> 1;          // k-tile 0..3
  const int kr = kt * 16 + (lane & 15);
  const float bk = conv_b[kr];

  short8 wh[4], wl[4];             // conv weights: shared by all 3 slabs
  {
    const int cbase = (lane >> 4) << 3;
#pragma unroll
    for (int cb32 = 0; cb32 < 4; ++cb32) {
      const float* wp = conv_w + (size_t)kr * 128 + cb32 * 32 + cbase;
      float4 u0 = *(const float4*)wp;
      float4 u1 = *(const float4*)(wp + 4);
      float fv[8] = {u0.x, u0.y, u0.z, u0.w, u1.x, u1.y, u1.z, u1.w};
      union { u16 u[8]; short8 v; } hh, ll;
#pragma unroll
      for (int j = 0; j < 8; ++j) {
        u16 h = f2bf(fv[j]);
        hh.u[j] = h;
        ll.u[j] = f2bf(fv[j] - bf2f(h));
      }
      wh[cb32] = hh.v; wl[cb32] = ll.v;
    }
  }

  float4v pacc[3][4];
#pragma unroll
  for (int si = 0; si < 3; ++si)
#pragma unroll
    for (int i = 0; i < 4; ++i) pacc[si][i] = (float4v){0.f, 0.f, 0.f, 0.f};
  float pak[3] = {0.f, 0.f, 0.f};

  // ---- prologue: load cc=0 x for all 3 slabs ----
  float2 xr[3][4];
#pragma unroll
  for (int s = 0; s < 4; ++s) {
    int e2 = t + 512 * s;
    int c = e2 >> 4, p = e2 & 15;
    int cl = 2 * p;
    int h = cl / 10, wi = cl - 10 * h;
    const float* ap = xn0 + (size_t)c * 14400 + h * 900 + wi;
#pragma unroll
    for (int si = 0; si < 3; ++si)
      xr[si][s] = *(const float2*)(ap + si * 10);
  }

  for (int cc = 0; cc < 5; ++cc) {
    __syncthreads();                 // prev P-mfma (afr reads) done before restage
    // ---- stage all 3 slabs into LDS ----
#pragma unroll
    for (int s = 0; s < 4; ++s) {
      int e2 = t + 512 * s;
      int c = e2 >> 4, p = e2 & 15;
      int cl = 2 * p;
      int ip = (c >> 4) * 640 + (p >> 2) * 160 + (c & 15) * 8 + (cl & 7);
      int F = (p >> 3) * 4 + (c >> 5);
      int L = (((c >> 3) & 3) << 4) + (cl & 15);
      int i0 = F * 520 + L * 8 + (c & 7);
#pragma unroll
      for (int si = 0; si < 3; ++si) {
        u16 h0 = f2bf(xr[si][s].x), h1 = f2bf(xr[si][s].y);
        u16* xf = (u16*)(smem + si * 27136 + 8320);
        u16* xtf = (u16*)(smem + si * 27136);
        ushort2 pr; pr.x = h0; pr.y = h1;
        *(ushort2*)&xf[ip] = pr;
        xtf[i0] = h0;
        xtf[i0 + 8] = h1;
      }
    }
    // ---- issue next cc's loads; retire behind this cc's compute ----
    if (cc < 4) {
#pragma unroll
      for (int s = 0; s < 4; ++s) {
        int e2 = t + 512 * s;
        int c = e2 >> 4, p = e2 & 15;
        int g = (cc + 1) * 32 + 2 * p;
        int h = g / 10, wi = g - 10 * h;
        const float* ap = xn0 + (size_t)c * 14400 + h * 900 + wi;
#pragma unroll
        for (int si = 0; si < 3; ++si)
          xr[si][s] = *(const float2*)(ap + si * 10);
      }
    }
    __syncthreads();

    // ---- logits MFMA: 3 independent accumulation chains ----
    {
      float4v d0[3];
#pragma unroll
      for (int si = 0; si < 3; ++si) d0[si] = (float4v){0.f, 0.f, 0.f, 0.f};
#pragma unroll
      for (int cb32 = 0; cb32 < 4; ++cb32) {
#pragma unroll
        for (int si = 0; si < 3; ++si) {
          const u16* xtf = (const u16*)(smem + si * 27136);
          short8 xa = *(short8*)&xtf[(colt * 4 + cb32) * 520 + lane * 8];
          d0[si] = __builtin_amdgcn_mfma_f32_16x16x32_bf16(xa, wh[cb32], d0[si], 0, 0, 0);
          d0[si] = __builtin_amdgcn_mfma_f32_16x16x32_bf16(xa, wl[cb32], d0[si], 0, 0, 0);
        }
      }
      int colb = colt * 16 + ((lane >> 4) << 2);
#pragma unroll
      for (int si = 0; si < 3; ++si) {
        float* As = (float*)(smem + si * 27136 + 18560);
#pragma unroll
        for (int r = 0; r < 4; ++r)
          As[kr * 33 + colb + r] = d0[si][r] + bk;
      }
    }
    __syncthreads();

    // ---- softmax + a-frag per slab (wave-local: cols [4*w8, 4*w8+4)) ----
#pragma unroll
    for (int si = 0; si < 3; ++si) {
      float* As = (float*)(smem + si * 27136 + 18560);
      float* invs = (float*)(smem + si * 27136 + 27008);
      u16* afr = (u16*)(smem + si * 27136);
      {
        const int col4 = lane & 3;
        const int kq = lane >> 2;        // 16 groups of 4 k
        const int colg = w8 * 4 + col4;
        float m = -3.4e38f;
#pragma unroll
        for (int i = 0; i < 4; ++i) m = fmaxf(m, As[(kq * 4 + i) * 33 + colg]);
        m = fmaxf(m, __shfl_xor(m, 4));
        m = fmaxf(m, __shfl_xor(m, 8));
        m = fmaxf(m, __shfl_xor(m, 16));
        m = fmaxf(m, __shfl_xor(m, 32));
        float s = 0.f;
#pragma unroll
        for (int i = 0; i < 4; ++i) {
          int a = (kq * 4 + i) * 33 + colg;
          float e = __expf(As[a] - m);
          As[a] = e;
          s += e;
        }
        s += __shfl_xor(s, 4);
        s += __shfl_xor(s, 8);
        s += __shfl_xor(s, 16);
        s += __shfl_xor(s, 32);
        if (kq == 0) invs[colg] = 1.f / s;
      }
      {
        union { u16 u[4]; ushort4 v; } cvt;
        float paks = 0.f;
#pragma unroll
        for (int j = 0; j < 4; ++j) {
          float a = As[lane * 33 + w8 * 4 + j] * invs[w8 * 4 + j];
          paks += a;
          cvt.u[j] = f2bf(a);
        }
        pak[si] += paks;
        int dst = ((lane >> 4) * 64 + ((w8 >> 1) << 4) + (lane & 15)) * 8 + (w8 & 1) * 4;
        *(ushort4*)&afr[dst] = cvt.v;
      }
    }
    __syncthreads();

    // ---- P MFMA: wave (kt, w8&1) owns k-tile kt, 4 of 8 c-tiles; x3 slabs ----
#pragma unroll
    for (int si = 0; si < 3; ++si) {
      const u16* afr = (const u16*)(smem + si * 27136);
      const u16* xf = (const u16*)(smem + si * 27136 + 8320);
      short8 aa = *(short8*)&afr[((w8 >> 1) * 64 + lane) * 8];
#pragma unroll
      for (int c4 = 0; c4 < 4; ++c4) {
        int ct = (w8 & 1) * 4 + c4;
        short8 xb = *(short8*)&xf[ct * 640 + (lane >> 4) * 160 + (lane & 15) * 8];
        pacc[si][c4] = __builtin_amdgcn_mfma_f32_16x16x32_bf16(aa, xb, pacc[si][c4], 0, 0, 0);
      }
    }
  }

  {
    int krow = (w8 >> 1) * 16 + ((lane >> 4) << 2);
    int c0 = (w8 & 1) * 64 + (lane & 15);
#pragma unroll
    for (int si = 0; si < 3; ++si) {
      float* Pp = P + (size_t)(n * NCB + 3 * q + si) * DDIM;
#pragma unroll
      for (int c4 = 0; c4 < 4; ++c4)
#pragma unroll
        for (int r = 0; r < 4; ++r)
          Pp[(krow + r) * 128 + c0 + c4 * 16] = pacc[si][c4][r];
    }
  }
  __syncthreads();                 // all As reads done before pasum overlays As
#pragma unroll
  for (int si = 0; si < 3; ++si)
    ((float*)(smem + si * 27136 + 18560))[t] = pak[si];
  __syncthreads();
  if (t < 64) {
#pragma unroll
    for (int si = 0; si < 3; ++si) {
      const float* pasum = (const float*)(smem + si * 27136 + 18560);
      float s = 0.f;
#pragma unroll
      for (int i = 0; i < 8; ++i) s += pasum[t + 64 * i];
      PA[(size_t)(n * NCB + 3 * q + si) * 64 + t] = s;
    }
  }
}

// ---------------------------------------------------------------------------
// K2: R5-R9 form. Traffic- and TLP-insensitive; at its floor. Unchanged.
// ---------------------------------------------------------------------------
__global__ __launch_bounds__(256) void k2_vlad(
    const float* __restrict__ P, const float* __restrict__ PA,
    const float* __restrict__ centers, u16* __restrict__ vlad16,
    float* __restrict__ gss)            // [240][8]
{
  __shared__ float Ak[8];
  __shared__ float red[4];
  const int bx0 = blockIdx.x;                    // [0,1920)
  const int id = (bx0 & 7) * 240 + (bx0 >> 3);   // XCD pin: n = bx0&7
  const int n = id / 240;
  const int rem = id - n * 240;
  const int wt = rem >> 3, eb = rem & 7;
  const int win = n * NT + wt;
  const int t = threadIdx.x;

  if (t < 32) {
    int kk = t >> 2, ii = t & 3;
    float s = 0.f;
#pragma unroll
    for (int ss = 0; ss < 5; ++ss) {
      int i = ii + 4 * ss;
      int cb = (3 * wt + 80 + i) % 90;
      s += PA[((size_t)n * NCB + cb) * 64 + eb * 8 + kk];
    }
    s += __shfl_xor(s, 1);
    s += __shfl_xor(s, 2);
    if (ii == 0) Ak[kk] = s;
  }
  __syncthreads();

  const int e0 = eb * 1024 + t * 4;     // global (k,c) offset in [0,8192)
  const float* base = P + (size_t)n * NCB * DDIM + e0;
  float v[4];
#pragma unroll
  for (int j = 0; j < 4; ++j) v[j] = 0.f;
#pragma unroll 5
  for (int i = 0; i < 20; ++i) {
    int cb = (3 * wt + 80 + i) % 90;
    float4 u0 = *(const float4*)(base + (size_t)cb * DDIM);
    v[0] += u0.x; v[1] += u0.y; v[2] += u0.z; v[3] += u0.w;
  }

  const float A = Ak[t >> 5];           // k_local = t/32
  const float* ce = centers + e0;
  float ss8 = 0.f;
#pragma unroll
  for (int j = 0; j < 4; ++j) {
    float val = v[j] - ce[j] * A;
    v[j] = val;
    ss8 += val * val;
  }
  // per-k (32-thread group) reduction for intra-norm
  float ssg = ss8;
  ssg += __shfl_xor(ssg, 1);
  ssg += __shfl_xor(ssg, 2);
  ssg += __shfl_xor(ssg, 4);
  ssg += __shfl_xor(ssg, 8);
  ssg += __shfl_xor(ssg, 16);
  float rn = 1.f / fmaxf(sqrtf(ssg), EPSF);
  // block-wide sum of normalized squares (for global norm)
  float ts = ss8 * rn * rn;
  ts += __shfl_xor(ts, 1);
  ts += __shfl_xor(ts, 2);
  ts += __shfl_xor(ts, 4);
  ts += __shfl_xor(ts, 8);
  ts += __shfl_xor(ts, 16);
  ts += __shfl_xor(ts, 32);
  if ((t & 63) == 0) red[t >> 6] = ts;
  __syncthreads();
  if (t == 0) gss[(size_t)win * 8 + eb] = red[0] + red[1] + red[2] + red[3];

  union { u16 u[4]; ushort4 v4; } o;
#pragma unroll
  for (int j = 0; j < 4; ++j) o.u[j] = f2bf(v[j] * rn);
  *(ushort4*)(vlad16 + (size_t)win * DDIM + e0) = o.v4;
}

// ---------------------------------------------------------------------------
// K3 (MFMA): R6-R9 form (3 rt-tiles per block, XCD-pinned weight slices).
// Unchanged.
// ---------------------------------------------------------------------------
__global__ __launch_bounds__(256) void k3_gemm(
    const u16* __restrict__ vlad16, const float* __restrict__ gss,
    const float* __restrict__ mlp_w, float* __restrict__ part)
{
  __shared__ float ga[48];
  const int bx = blockIdx.x;         // [0,320)
  const int xcd = bx & 7;
  const int q = bx >> 3;             // [0,40)
  const int rtg = q % 5;             // rt-group: rows [rtg*48, rtg*48+48)
  const int h = (q / 5) * 8 + xcd;   // [0,64): same h -> same XCD, adjacent
  const int ot = h & 1;              // o half
  const int ks = h >> 1;             // K-slice of 256
  const int t = threadIdx.x;
  const int lane = t & 63;
  const int w = t >> 6;

  if (t < 48) {
    int r = rtg * 48 + t;
    float s = 0.f;
#pragma unroll
    for (int j = 0; j < 8; ++j) s += gss[(size_t)r * 8 + j];
    ga[t] = 1.f / fmaxf(sqrtf(s), EPSF);
  }
  __syncthreads();

  const int m = lane & 15;
  const int kg = lane >> 4;
  const int d0 = ks * 256 + kg * 8;
  const u16* a0 = vlad16 + (size_t)(rtg * 48 + m) * DDIM + d0;

  float4v acc[3][2];
#pragma unroll
  for (int mi = 0; mi < 3; ++mi)
#pragma unroll
    for (int i = 0; i < 2; ++i) acc[mi][i] = (float4v){0.f, 0.f, 0.f, 0.f};

#pragma unroll
  for (int ko = 0; ko < 8; ++ko) {
    short8 a[3];
#pragma unroll
    for (int mi = 0; mi < 3; ++mi)
      a[mi] = *(const short8*)(a0 + (size_t)(mi * 16) * DDIM + ko * 32);
#pragma unroll
    for (int nt = 0; nt < 2; ++nt) {
      int o = ot * 128 + w * 32 + nt * 16 + m;
      const float* wrow = mlp_w + (size_t)o * DDIM + d0 + ko * 32;
      float4 u0 = *(const float4*)wrow;
      float4 u1 = *(const float4*)(wrow + 4);
      union { u16 u[8]; short8 v; } bb;
      bb.u[0] = f2bf(u0.x); bb.u[1] = f2bf(u0.y); bb.u[2] = f2bf(u0.z); bb.u[3] = f2bf(u0.w);
      bb.u[4] = f2bf(u1.x); bb.u[5] = f2bf(u1.y); bb.u[6] = f2bf(u1.z); bb.u[7] = f2bf(u1.w);
#pragma unroll
      for (int mi = 0; mi < 3; ++mi)
        acc[mi][nt] = __builtin_amdgcn_mfma_f32_16x16x32_bf16(a[mi], bb.v, acc[mi][nt], 0, 0, 0);
    }
  }

  float* pp = part + ((size_t)ks * 240 + rtg * 48) * ODIM;
#pragma unroll
  for (int mi = 0; mi < 3; ++mi)
#pragma unroll
    for (int nt = 0; nt < 2; ++nt) {
      int o = ot * 128 + w * 32 + nt * 16 + m;
#pragma unroll
      for (int r = 0; r < 4; ++r) {
        int rl = mi * 16 + kg * 4 + r;
        pp[rl * ODIM + o] = acc[mi][nt][r] * ga[rl];
      }
    }
}

// ---------------------------------------------------------------------------
// K4: R5-R9 form (1024 threads, 4-way split sum). At its floor. Unchanged.
// ---------------------------------------------------------------------------
__global__ __launch_bounds__(1024) void k4_out(
    const float* __restrict__ part, const float* __restrict__ bias,
    float* __restrict__ out)
{
  __shared__ float acc[4][256];
  __shared__ float red[4];
  const int r = blockIdx.x;
  const int t = threadIdx.x;
  const int o = t & 255, sq = t >> 8;

  float v = 0.f;
#pragma unroll
  for (int s = 0; s < 8; ++s)
    v += part[((size_t)(sq * 8 + s) * 240 + r) * ODIM + o];
  acc[sq][o] = v;
  __syncthreads();

  float ss = 0.f;
  if (t < 256) {
    v = acc[0][o] + acc[1][o] + acc[2][o] + acc[3][o] + bias[o];
    ss = v * v;
    ss += __shfl_xor(ss, 32);
    ss += __shfl_xor(ss, 16);
    ss += __shfl_xor(ss, 8);
    ss += __shfl_xor(ss, 4);
    ss += __shfl_xor(ss, 2);
    ss += __shfl_xor(ss, 1);
    if ((o & 63) == 0) red[t >> 6] = ss;
  }
  __syncthreads();
  if (t < 256) {
    float total = red[0] + red[1] + red[2] + red[3];
    out[(size_t)r * ODIM + o] = v / fmaxf(sqrtf(total), EPSF);
  }
}

// ---------------------------------------------------------------------------
extern "C" void kernel_launch(void* const* d_in, const int* in_sizes, int n_in,
                              void* d_out, int out_size, void* d_ws, size_t ws_size,
                              hipStream_t stream) {
  const float* x       = (const float*)d_in[0];
  const float* centers = (const float*)d_in[1];
  const float* conv_w  = (const float*)d_in[2];
  const float* conv_b  = (const float*)d_in[3];
  const float* mlp_w   = (const float*)d_in[4];
  const float* mlp_b   = (const float*)d_in[5];
  float* out = (float*)d_out;

  float* ws     = (float*)d_ws;
  float* P      = ws;                       // 5,898,240 floats (23.6 MB)
  float* PA     = ws + 5898240;             // 46,080 floats
  u16*   vlad16 = (u16*)(ws + 5944320);     // 240*8192 u16 (3.9 MB)
  float* gss    = (float*)(ws + 6927360);   // 240*8 floats
  float* part   = ws;                       // [32][240][256] overlays dead P

  k1_assign<<<dim3(240),        dim3(512),  0, stream>>>(x, conv_w, conv_b, P, PA);
  k2_vlad  <<<dim3(8 * NT * 8), dim3(256),  0, stream>>>(P, PA, centers, vlad16, gss);
  k3_gemm  <<<dim3(320),        dim3(256),  0, stream>>>(vlad16, gss, mlp_w, part);
  k4_out   <<<dim3(240),        dim3(1024), 0, stream>>>(part, mlp_b, out);
}